// Round 1
// baseline (265.027 us; speedup 1.0000x reference)
//
#include <hip/hip_runtime.h>

// Problem constants (fixed by setup_inputs: B=64, Z=256, F=128, T=2048, C=5)
#define BATCH   64
#define FDIM    128
#define TDIM    2048
#define CDIM    5
#define ZN      (64 * 256)   // mean / log_var element count

// Kernel 1: mse partial = sum over (b,t) of (sum_f (o[b,0,f,t] - tg[b,0,f,t]))^2
// One thread per (b,t) column. Consecutive threads -> consecutive t -> coalesced.
// Only channel 0 (real part) is ever read.
__global__ __launch_bounds__(256) void mse_kernel(const float* __restrict__ o,
                                                  const float* __restrict__ tg,
                                                  float* __restrict__ acc) {
    int gid = blockIdx.x * 256 + threadIdx.x;     // 0 .. B*T-1
    int b = gid >> 11;                            // / TDIM
    int t = gid & (TDIM - 1);
    const float* po = o  + (size_t)b * (2 * FDIM * TDIM) + t;
    const float* pt = tg + (size_t)b * (2 * FDIM * TDIM) + t;
    float s = 0.0f;
#pragma unroll 8
    for (int f = 0; f < FDIM; ++f) {
        s += po[(size_t)f * TDIM] - pt[(size_t)f * TDIM];
    }
    float val = s * s;

    __shared__ float red[256];
    red[threadIdx.x] = val;
    __syncthreads();
#pragma unroll
    for (int off = 128; off > 0; off >>= 1) {
        if (threadIdx.x < (unsigned)off) red[threadIdx.x] += red[threadIdx.x + off];
        __syncthreads();
    }
    if (threadIdx.x == 0) atomicAdd(acc, red[0]);
}

// Kernel 2 (single block, 1024 threads): KLD + cross-entropy + final combine.
// Runs after kernel 1 by stream ordering, so acc[0] holds the full MSE/4 sum.
__global__ __launch_bounds__(1024) void tail_kernel(const float* __restrict__ mean,
                                                    const float* __restrict__ log_var,
                                                    const float* __restrict__ oclas,
                                                    const int* __restrict__ tclas,
                                                    const float* __restrict__ w,
                                                    const float* __restrict__ mse_acc,
                                                    float* __restrict__ out) {
    int tid = threadIdx.x;

    // KLD: -0.5 * sum(1 + lv - m^2 - exp(lv))
    float kld = 0.0f;
    for (int i = tid; i < ZN; i += 1024) {
        float m  = mean[i];
        float lv = log_var[i];
        kld += -0.5f * (1.0f + lv - m * m - expf(lv));
    }

    // Cross-entropy, one row per thread for tid < BATCH
    float cl = 0.0f;
    if (tid < BATCH) {
        const float* row = oclas + tid * CDIM;
        float mx = row[0];
#pragma unroll
        for (int c = 1; c < CDIM; ++c) mx = fmaxf(mx, row[c]);
        float se = 0.0f;
#pragma unroll
        for (int c = 0; c < CDIM; ++c) se += expf(row[c] - mx);
        int tc = tclas[tid];
        cl = -(row[tc] - mx - logf(se));
    }

    __shared__ float rk[1024];
    __shared__ float rc[1024];
    rk[tid] = kld;
    rc[tid] = cl;
    __syncthreads();
#pragma unroll
    for (int off = 512; off > 0; off >>= 1) {
        if (tid < off) {
            rk[tid] += rk[tid + off];
            rc[tid] += rc[tid + off];
        }
        __syncthreads();
    }

    if (tid == 0) {
        float mse = 4.0f * mse_acc[0];               // ISSQ scale 2 on each signal
        float clas_loss = rc[0] / (float)BATCH;      // mean reduction
        out[0] = w[0] * mse + w[1] * rk[0] + w[2] * clas_loss;
    }
}

extern "C" void kernel_launch(void* const* d_in, const int* in_sizes, int n_in,
                              void* d_out, int out_size, void* d_ws, size_t ws_size,
                              hipStream_t stream) {
    const float* mean     = (const float*)d_in[0];
    const float* log_var  = (const float*)d_in[1];
    const float* orec     = (const float*)d_in[2];
    const float* oclas    = (const float*)d_in[3];
    const float* trec     = (const float*)d_in[4];
    const int*   tclas    = (const int*)d_in[5];
    // d_in[6] = batch_size scalar, d_in[7] = img_size scalar (device mem; constants hardcoded)
    const float* w        = (const float*)d_in[8];
    float* out            = (float*)d_out;
    float* acc            = (float*)d_ws;   // one float accumulator

    // Workspace is poisoned 0xAA before every launch — zero the accumulator.
    hipMemsetAsync(acc, 0, sizeof(float), stream);

    const int nCols  = BATCH * TDIM;        // 131072
    const int blocks = nCols / 256;         // 512
    mse_kernel<<<blocks, 256, 0, stream>>>(orec, trec, acc);
    tail_kernel<<<1, 1024, 0, stream>>>(mean, log_var, oclas, tclas, w, acc, out);
}

// Round 2
// 261.958 us; speedup vs baseline: 1.0117x; 1.0117x over previous
//
#include <hip/hip_runtime.h>

// Problem constants (fixed by setup_inputs: B=64, Z=256, F=128, T=2048, C=5)
#define BATCH   64
#define FDIM    128
#define TDIM    2048
#define CDIM    5
#define ZN      (64 * 256)     // mean / log_var element count
#define NBLK    1024           // mse partial blocks: 64 b * 16 t-tiles

// Kernel 1: per-block partial of  sum_{b,t} ( sum_f (o[b,0,f,t] - tg[b,0,f,t]) )^2
// Block = (b, 128-wide t tile). 256 threads = 8 f-groups x 32 float4 columns.
// Each thread: 16 iterations x 2 float4 loads (o and tg), fully coalesced.
// Writes partial[blockIdx] — every slot written, so no zero-init of d_ws needed.
__global__ __launch_bounds__(256) void mse_partials(const float* __restrict__ o,
                                                    const float* __restrict__ tg,
                                                    float* __restrict__ partial) {
    const int blk  = blockIdx.x;        // 0..1023
    const int b    = blk >> 4;          // / 16
    const int tile = blk & 15;          // 16 tiles of 128 t
    const int tid  = threadIdx.x;
    const int fg   = tid >> 5;          // 0..7  (f-group of 16 rows)
    const int tq   = tid & 31;          // 0..31 (float4 column slot)

    const size_t base = (size_t)b * (2 * FDIM * TDIM) + (size_t)(fg * 16) * TDIM
                      + tile * 128 + tq * 4;
    const float* po = o  + base;
    const float* pt = tg + base;

    float4 s = make_float4(0.f, 0.f, 0.f, 0.f);
#pragma unroll
    for (int i = 0; i < 16; ++i) {
        float4 a = *(const float4*)(po + (size_t)i * TDIM);
        float4 c = *(const float4*)(pt + (size_t)i * TDIM);
        s.x += a.x - c.x;
        s.y += a.y - c.y;
        s.z += a.z - c.z;
        s.w += a.w - c.w;
    }

    __shared__ float4 red[256];
    __shared__ float  red2[32];
    red[tid] = s;
    __syncthreads();

    if (tid < 32) {
        float4 c = red[tid];
#pragma unroll
        for (int g = 1; g < 8; ++g) {
            float4 r = red[g * 32 + tid];
            c.x += r.x; c.y += r.y; c.z += r.z; c.w += r.w;
        }
        // square per t-column (each component is one column's full f-sum)
        red2[tid] = c.x * c.x + c.y * c.y + c.z * c.z + c.w * c.w;
    }
    __syncthreads();

    if (tid == 0) {
        float acc = 0.f;
#pragma unroll
        for (int i = 0; i < 32; ++i) acc += red2[i];
        partial[blk] = acc;
    }
}

// Kernel 2 (single block, 1024 threads): reduce partials + KLD + CE + combine.
__global__ __launch_bounds__(1024) void tail_kernel(const float* __restrict__ mean,
                                                    const float* __restrict__ log_var,
                                                    const float* __restrict__ oclas,
                                                    const int* __restrict__ tclas,
                                                    const float* __restrict__ w,
                                                    const float* __restrict__ partial,
                                                    float* __restrict__ out) {
    const int tid = threadIdx.x;

    // MSE partial (one per thread)
    float ms = partial[tid];

    // KLD: -0.5 * sum(1 + lv - m^2 - exp(lv)); ZN/1024 = 16 elems per thread
    float kld = 0.0f;
#pragma unroll
    for (int i = 0; i < ZN / 1024; ++i) {
        int idx = tid + i * 1024;
        float m  = mean[idx];
        float lv = log_var[idx];
        kld += -0.5f * (1.0f + lv - m * m - expf(lv));
    }

    // Cross-entropy, one row per thread for tid < BATCH
    float cl = 0.0f;
    if (tid < BATCH) {
        const float* row = oclas + tid * CDIM;
        float mx = row[0];
#pragma unroll
        for (int c = 1; c < CDIM; ++c) mx = fmaxf(mx, row[c]);
        float se = 0.0f;
#pragma unroll
        for (int c = 0; c < CDIM; ++c) se += expf(row[c] - mx);
        int tc = tclas[tid];
        cl = -(row[tc] - mx - logf(se));
    }

    __shared__ float rm[1024];
    __shared__ float rk[1024];
    __shared__ float rc[1024];
    rm[tid] = ms;
    rk[tid] = kld;
    rc[tid] = cl;
    __syncthreads();
#pragma unroll
    for (int off = 512; off > 0; off >>= 1) {
        if (tid < off) {
            rm[tid] += rm[tid + off];
            rk[tid] += rk[tid + off];
            rc[tid] += rc[tid + off];
        }
        __syncthreads();
    }

    if (tid == 0) {
        float mse = 4.0f * rm[0];                 // ISSQ scale 2 on each signal
        float clas_loss = rc[0] / (float)BATCH;   // mean reduction
        out[0] = w[0] * mse + w[1] * rk[0] + w[2] * clas_loss;
    }
}

extern "C" void kernel_launch(void* const* d_in, const int* in_sizes, int n_in,
                              void* d_out, int out_size, void* d_ws, size_t ws_size,
                              hipStream_t stream) {
    const float* mean    = (const float*)d_in[0];
    const float* log_var = (const float*)d_in[1];
    const float* orec    = (const float*)d_in[2];
    const float* oclas   = (const float*)d_in[3];
    const float* trec    = (const float*)d_in[4];
    const int*   tclas   = (const int*)d_in[5];
    // d_in[6] = batch_size, d_in[7] = img_size (constants hardcoded)
    const float* w       = (const float*)d_in[8];
    float* out           = (float*)d_out;
    float* partial       = (float*)d_ws;   // NBLK floats, all slots overwritten

    mse_partials<<<NBLK, 256, 0, stream>>>(orec, trec, partial);
    tail_kernel<<<1, 1024, 0, stream>>>(mean, log_var, oclas, tclas, w, partial, out);
}